// Round 11
// baseline (25.818 us; speedup 1.0000x reference)
//
#include <hip/hip_runtime.h>
#include <cstdint>
#include <cstddef>

typedef _Float16 half8 __attribute__((ext_vector_type(8)));
typedef float f32x4 __attribute__((ext_vector_type(4)));

static constexpr int kN  = 256;          // state dim (N == K)
static constexpr int kKS = 8;            // k-steps of 32
static constexpr size_t kABytes = (size_t)kN * kN * 2;  // 128 KiB packed f16 A

// Pack A_stacked[t] (fp32 row-major [n][k]) into f16 MFMA B-fragment order:
// a16[((nt*8 + ks)*64 + l)*8 + j] = A[nt*16 + (l&15)][ks*32 + (l>>4)*8 + j]
__global__ __launch_bounds__(256) void hippo_prep(
    const float* __restrict__ A_stacked, const int* __restrict__ tptr,
    _Float16* __restrict__ a16)
{
    const int t = tptr[0];
    const float* __restrict__ A = A_stacked + (size_t)t * kN * kN;
    const int tid = blockIdx.x * 256 + threadIdx.x;   // 0..8191
    const int nt = tid >> 9;
    const int ks = (tid >> 6) & 7;
    const int l  = tid & 63;
    const int row = nt * 16 + (l & 15);
    const int k0  = ks * 32 + ((l >> 4) << 3);
    const float* __restrict__ src = A + row * kN + k0;
    f32x4 v0 = *(const f32x4*)(src);
    f32x4 v1 = *(const f32x4*)(src + 4);
    half8 h;
    h[0] = (_Float16)v0[0]; h[1] = (_Float16)v0[1];
    h[2] = (_Float16)v0[2]; h[3] = (_Float16)v0[3];
    h[4] = (_Float16)v1[0]; h[5] = (_Float16)v1[1];
    h[6] = (_Float16)v1[2]; h[7] = (_Float16)v1[3];
    ((half8*)a16)[tid] = h;
}

// out[m][n] = sum_k c[m][k] * A_t[n][k] + b[n] * f[m]
// Block: 512 thr (8 waves = 4m x 2n), full packed B in 128 KiB LDS (DMA once),
// TWO 64-row m-slabs processed sequentially. c(iter1) loads are issued right
// after the barrier so their HBM latency hides under iter0's cvt+MFMA+stores.
__global__ __launch_bounds__(512, 2) void hippo_gemm(
    const float* __restrict__ c, const float* __restrict__ f,
    const float* __restrict__ Bst, const int* __restrict__ tptr,
    const _Float16* __restrict__ a16, float* __restrict__ out)
{
    extern __shared__ char lds_raw[];

    const int tid  = threadIdx.x;
    const int l    = tid & 63;
    const int wid  = tid >> 6;          // 0..7
    const int wm   = wid & 3;           // m-sub 0..3 (16 rows)
    const int wn   = wid >> 2;          // n-half 0..1 (128 cols)
    const int lo16 = l & 15;
    const int hi4  = l >> 4;
    const int m0   = blockIdx.x * 128 + wm * 16;   // iter-0 rows
    const int m1   = m0 + 64;                      // iter-1 rows
    const int ntb  = wn * 8;                       // first n-tile of this wave

    // ---- 1) c loads for iter 0 (deepest latency; issue first) ----
    const float* __restrict__ cp0 = c + (size_t)(m0 + lo16) * kN + (hi4 << 3);
    f32x4 cv0[kKS], cv1[kKS];
    #pragma unroll
    for (int ks = 0; ks < kKS; ++ks) {
        cv0[ks] = *(const f32x4*)(cp0 + ks * 32);
        cv1[ks] = *(const f32x4*)(cp0 + ks * 32 + 4);
    }

    // ---- 2) DMA-stage full packed B (128 KiB) into LDS ----
    #pragma unroll
    for (int i = 0; i < 16; ++i) {
        const size_t off = (size_t)(i * 8 + wid) * 1024 + (size_t)l * 16;
        __builtin_amdgcn_global_load_lds(
            (const __attribute__((address_space(1))) void*)((const char*)a16 + off),
            (__attribute__((address_space(3))) void*)(lds_raw + off),
            16, 0, 0);
    }

    // ---- 3) bias loads (both iterations) ----
    const int t = tptr[0];
    const float* __restrict__ brow = Bst + (size_t)t * kN + wn * 128;
    float bvs[8];
    #pragma unroll
    for (int nt = 0; nt < 8; ++nt) bvs[nt] = brow[nt * 16 + lo16];
    float fv0[4], fv1[4];
    #pragma unroll
    for (int r = 0; r < 4; ++r) {
        fv0[r] = f[m0 + (hi4 << 2) + r];
        fv1[r] = f[m1 + (hi4 << 2) + r];
    }

    __syncthreads();   // drains c0 + DMA together (parallel latencies)

    // ---- 4) issue c loads for iter 1 (fly under iter-0 compute/stores) ----
    const float* __restrict__ cp1 = c + (size_t)(m1 + lo16) * kN + (hi4 << 3);
    f32x4 dv0[kKS], dv1[kKS];
    #pragma unroll
    for (int ks = 0; ks < kKS; ++ks) {
        dv0[ks] = *(const f32x4*)(cp1 + ks * 32);
        dv1[ks] = *(const f32x4*)(cp1 + ks * 32 + 4);
    }

    // ---- 5) iter 0: cvt -> MFMA (ks-outer) -> streamed stores ----
    half8 af[kKS];
    #pragma unroll
    for (int ks = 0; ks < kKS; ++ks) {
        af[ks][0] = (_Float16)cv0[ks][0]; af[ks][1] = (_Float16)cv0[ks][1];
        af[ks][2] = (_Float16)cv0[ks][2]; af[ks][3] = (_Float16)cv0[ks][3];
        af[ks][4] = (_Float16)cv1[ks][0]; af[ks][5] = (_Float16)cv1[ks][1];
        af[ks][6] = (_Float16)cv1[ks][2]; af[ks][7] = (_Float16)cv1[ks][3];
    }
    const half8* __restrict__ Bs = (const half8*)lds_raw;
    f32x4 acc[8];
    #pragma unroll
    for (int i = 0; i < 8; ++i) acc[i] = (f32x4){0.f, 0.f, 0.f, 0.f};
    #pragma unroll
    for (int ks = 0; ks < kKS; ++ks) {
        #pragma unroll
        for (int nt = 0; nt < 8; ++nt) {
            half8 bf = Bs[((ntb + nt) * kKS + ks) * 64 + l];
            acc[nt] = __builtin_amdgcn_mfma_f32_16x16x32_f16(af[ks], bf, acc[nt], 0, 0, 0);
        }
    }
    float* __restrict__ ob0 = out + (size_t)(m0 + (hi4 << 2)) * kN + wn * 128 + lo16;
    #pragma unroll
    for (int nt = 0; nt < 8; ++nt) {
        #pragma unroll
        for (int r = 0; r < 4; ++r)
            ob0[(size_t)r * kN + nt * 16] = acc[nt][r] + bvs[nt] * fv0[r];
    }

    // ---- 6) iter 1: cvt (waits c1 per-use) -> MFMA -> stores ----
    half8 ag[kKS];
    #pragma unroll
    for (int ks = 0; ks < kKS; ++ks) {
        ag[ks][0] = (_Float16)dv0[ks][0]; ag[ks][1] = (_Float16)dv0[ks][1];
        ag[ks][2] = (_Float16)dv0[ks][2]; ag[ks][3] = (_Float16)dv0[ks][3];
        ag[ks][4] = (_Float16)dv1[ks][0]; ag[ks][5] = (_Float16)dv1[ks][1];
        ag[ks][6] = (_Float16)dv1[ks][2]; ag[ks][7] = (_Float16)dv1[ks][3];
    }
    f32x4 acc2[8];
    #pragma unroll
    for (int i = 0; i < 8; ++i) acc2[i] = (f32x4){0.f, 0.f, 0.f, 0.f};
    #pragma unroll
    for (int ks = 0; ks < kKS; ++ks) {
        #pragma unroll
        for (int nt = 0; nt < 8; ++nt) {
            half8 bf = Bs[((ntb + nt) * kKS + ks) * 64 + l];
            acc2[nt] = __builtin_amdgcn_mfma_f32_16x16x32_f16(ag[ks], bf, acc2[nt], 0, 0, 0);
        }
    }
    float* __restrict__ ob1 = out + (size_t)(m1 + (hi4 << 2)) * kN + wn * 128 + lo16;
    #pragma unroll
    for (int nt = 0; nt < 8; ++nt) {
        #pragma unroll
        for (int r = 0; r < 4; ++r)
            ob1[(size_t)r * kN + nt * 16] = acc2[nt][r] + bvs[nt] * fv1[r];
    }
}

extern "C" void kernel_launch(void* const* d_in, const int* in_sizes, int n_in,
                              void* d_out, int out_size, void* d_ws, size_t ws_size,
                              hipStream_t stream) {
    const float* c   = (const float*)d_in[0];
    const float* f   = (const float*)d_in[1];
    const float* A   = (const float*)d_in[2];
    const float* B   = (const float*)d_in[3];
    const int*   t   = (const int*)d_in[4];
    float* out = (float*)d_out;
    _Float16* a16 = (_Float16*)d_ws;   // 128 KiB packed A[t] f16

    const int batch = in_sizes[0] / kN;   // 32768

    hipFuncSetAttribute((const void*)hippo_gemm,
                        hipFuncAttributeMaxDynamicSharedMemorySize,
                        (int)kABytes);

    hipLaunchKernelGGL(hippo_prep, dim3(32), dim3(256), 0, stream, A, t, a16);
    hipLaunchKernelGGL(hippo_gemm, dim3(batch / 128), dim3(512), kABytes, stream,
                       c, f, B, t, a16, out);
}